// Round 17
// baseline (235.197 us; speedup 1.0000x reference)
//
#include <hip/hip_runtime.h>
#include <hip/hip_cooperative_groups.h>

namespace cg = cooperative_groups;

// GCN 2-layer encoder: N=50000 nodes, E=800000 edges, 256 -> 128 -> 64.
// Round 17: entire CSR build (wtrans + bin_count + bin_scan + bin_scatter +
// fine sort) fused into ONE cooperative kernel with grid.sync() phases —
// 9 -> 5 launches, per-block edge chunks stay L2-hot across phases.
// GEMMs + seg_agg byte-identical to round 16 (139us).

#define IN_C 256
#define HID 128
#define OUTC 64
#define NBLK 256    // cooperative grid blocks

typedef __attribute__((ext_vector_type(8))) short short8;
typedef __attribute__((ext_vector_type(4))) float f32x4;

// ---- async global -> LDS, 16B per lane (dst = wave-uniform base) -----------
__device__ __forceinline__ void gload_lds16(const void* src, void* dst) {
    __builtin_amdgcn_global_load_lds(
        (const __attribute__((address_space(1))) unsigned int*)src,
        (__attribute__((address_space(3))) unsigned int*)dst, 16, 0, 0);
}

// ---- fp32 -> bf16 hi/lo split (RTN, exact residual) ------------------------
__device__ __forceinline__ void bf16split(float f, ushort& h, ushort& l) {
    unsigned u = __float_as_uint(f);
    h = (ushort)(u >> 16);
    float hf = __uint_as_float(u & 0xFFFF0000u);
    unsigned v = __float_as_uint(f - hf);
    l = (ushort)((v + 0x7FFF + ((v >> 16) & 1)) >> 16);
}

// 8x fp32 -> hi/lo bf16 short8, trunc-lo variant
__device__ __forceinline__ void cvt8(float4 f0, float4 f1, short8& hi8, short8& lo8) {
    float ff[8];
    *(float4*)&ff[0] = f0; *(float4*)&ff[4] = f1;
    unsigned* hp = (unsigned*)&hi8;
    unsigned* lp = (unsigned*)&lo8;
    #pragma unroll
    for (int i = 0; i < 4; ++i) {
        unsigned u0 = __float_as_uint(ff[2 * i]), u1 = __float_as_uint(ff[2 * i + 1]);
        unsigned hf0 = u0 & 0xFFFF0000u, hf1 = u1 & 0xFFFF0000u;
        hp[i] = (u0 >> 16) | hf1;
        float r0 = ff[2 * i]     - __uint_as_float(hf0);
        float r1 = ff[2 * i + 1] - __uint_as_float(hf1);
        lp[i] = (__float_as_uint(r0) >> 16) | (__float_as_uint(r1) & 0xFFFF0000u);
    }
}

__device__ __forceinline__ ushort f2bf(float f) {
    unsigned u = __float_as_uint(f);
    return (ushort)((u + 0x7FFF + ((u >> 16) & 1)) >> 16);
}
__device__ __forceinline__ float bf2f(ushort u) {
    return __uint_as_float((unsigned)u << 16);
}

// ---- edge index access (int64 vs int32, detected per block) ----------------
__device__ __forceinline__ int edge_at(const void* ei, long long idx, int is32) {
    return is32 ? ((const int*)ei)[idx] : (int)((const long long*)ei)[idx];
}

__device__ __forceinline__ int detect32(const void* ei) {
    const unsigned long long* p = (const unsigned long long*)ei;
    int is32 = 0;
    for (int i = 0; i < 64; ++i)
        if (p[i] >> 32) { is32 = 1; break; }
    return is32;
}

// ---- fused CSR build: wtrans + count + scan + scatter + fine (cooperative) -
__global__ __launch_bounds__(256) void csr_coop(const void* ei,
                                                const float* __restrict__ W1,
                                                const float* __restrict__ W2,
                                                ushort* __restrict__ wf1,
                                                ushort* __restrict__ wf2,
                                                ushort* __restrict__ h1sent,
                                                ushort* __restrict__ h2sent,
                                                int* __restrict__ blkcnt,
                                                int* __restrict__ bbase,
                                                int2* __restrict__ rp2,
                                                float* __restrict__ dis,
                                                unsigned* __restrict__ coarse,
                                                int* __restrict__ epk,
                                                int E, int N, int nb) {
    cg::grid_group grid = cg::this_grid();
    __shared__ int sh_a[256], sh_b[256], sh_c[256];
    __shared__ int s_is32;
    int b = blockIdx.x, t = threadIdx.x;
    int chunk = (E + NBLK - 1) / NBLK;
    long long s0 = (long long)b * chunk;
    long long s1 = s0 + chunk; if (s1 > E) s1 = E;

    // ---- phase A: wtrans (unit = t*256+b, ~41 active threads/block) + count
    {
        int id = t * 256 + b;   // 0..65535; valid wtrans units < 10432
        if (id < 8192) {
            int lane = id & 63, r = id >> 6;       // r = kidx*16 + nt*2 + pl
            int pl = r & 1, nt = (r >> 1) & 7, kidx = r >> 4;
            int n = nt * 16 + (lane & 15);
            int kb = kidx * 32 + (lane >> 4) * 8;
            ushort v[8];
            #pragma unroll
            for (int j = 0; j < 8; ++j) {
                ushort h, l; bf16split(W1[(kb + j) * HID + n], h, l);
                v[j] = pl ? l : h;
            }
            *(short8*)&wf1[(size_t)id * 8] = *(short8*)v;
        } else if (id < 10240) {
            int id2 = id - 8192;
            int lane = id2 & 63, r = id2 >> 6;     // r = kidx*8 + nt*2 + pl
            int pl = r & 1, nt = (r >> 1) & 3, kidx = r >> 3;
            int n = nt * 16 + (lane & 15);
            int kb = kidx * 32 + (lane >> 4) * 8;
            ushort v[8];
            #pragma unroll
            for (int j = 0; j < 8; ++j) {
                ushort h, l; bf16split(W2[(kb + j) * OUTC + n], h, l);
                v[j] = pl ? l : h;
            }
            *(short8*)&wf2[(size_t)id2 * 8] = *(short8*)v;
        } else if (id < 10368) {
            h1sent[id - 10240] = 0;
        } else if (id < 10432) {
            h2sent[id - 10368] = 0;
        }
    }
    {   // bin_count
        sh_a[t] = 0;
        if (t == 0) s_is32 = detect32(ei);
        __syncthreads();
        int is32 = s_is32;
        for (long long e = s0 + t; e < s1; e += 256) {
            int d = edge_at(ei, (long long)E + e, is32);
            atomicAdd(&sh_a[d >> 8], 1);
        }
        __syncthreads();
        if (t < nb) blkcnt[t * NBLK + b] = sh_a[t];
    }
    grid.sync();

    // ---- phase B: bucket scan (block 0) ------------------------------------
    if (b == 0) {
        int tot = 0;
        if (t < nb) {
            int4* p = (int4*)&blkcnt[t * NBLK];
            int run = 0;
            for (int i = 0; i < NBLK / 4; ++i) {
                int4 v = p[i]; int4 o;
                o.x = run; run += v.x; o.y = run; run += v.y;
                o.z = run; run += v.z; o.w = run; run += v.w;
                p[i] = o;
            }
            tot = run;
        }
        sh_b[t] = tot;
        __syncthreads();
        for (int d = 1; d < 256; d <<= 1) {
            int add = (t >= d) ? sh_b[t - d] : 0;
            __syncthreads();
            sh_b[t] += add;
            __syncthreads();
        }
        if (t < nb) {
            bbase[t] = sh_b[t] - tot;              // exclusive
            if (t == nb - 1) bbase[nb] = sh_b[t];  // = E
        }
    }
    grid.sync();

    // ---- phase C: scatter (edge chunk is L2-hot from phase A) --------------
    {
        if (t < nb) sh_a[t] = bbase[t] + blkcnt[t * NBLK + b];
        __syncthreads();
        int is32 = s_is32;
        for (long long e = s0 + t; e < s1; e += 256) {
            int s = edge_at(ei, e, is32);
            int d = edge_at(ei, (long long)E + e, is32);
            int p = atomicAdd(&sh_a[d >> 8], 1);
            coarse[p] = (unsigned)s | ((unsigned)(d & 255) << 17);
        }
    }
    grid.sync();

    // ---- phase D: per-bucket fine sort, padded segments (blocks < nb) ------
    if (b < nb) {
        int nb0 = b << 8;
        int e0b = bbase[b], e1b = bbase[b + 1];
        int obase0 = e0b + b * 4096;
        sh_a[t] = 0;
        __syncthreads();
        for (int e = e0b + t; e < e1b; e += 256)
            atomicAdd(&sh_a[(coarse[e] >> 17) & 0xFF], 1);
        __syncthreads();
        int cnt = sh_a[t];
        int pad = (cnt + 15) & ~15;
        sh_b[t] = pad;
        __syncthreads();
        for (int d = 1; d < 256; d <<= 1) {
            int add = (t >= d) ? sh_b[t - d] : 0;
            __syncthreads();
            sh_b[t] += add;
            __syncthreads();
        }
        int base = obase0 + sh_b[t] - pad;
        int node = nb0 + t;
        if (node < N) {
            rp2[node] = make_int2(base, pad);
            dis[node] = rsqrtf((float)cnt + 1.0f);   // +1 = self loop
        }
        sh_c[t] = base;
        __syncthreads();
        for (int e = e0b + t; e < e1b; e += 256) {
            unsigned r = coarse[e];
            int p = atomicAdd(&sh_c[(r >> 17) & 0xFF], 1);
            epk[p] = (int)(r & 0x1FFFF);
        }
        __syncthreads();
        for (int p = sh_c[t]; p < base + pad; ++p) epk[p] = N;   // sentinel
    }
}

// ---- GEMM1: Hs[N+1][128] = (X@W1)*dis (row-major bf16) ---------------------
__global__ __launch_bounds__(256) void gemm1_mfma(const float* __restrict__ X,
                                                  const ushort* __restrict__ wf1,
                                                  const float* __restrict__ dis,
                                                  ushort* __restrict__ HB, int N) {
    __shared__ float xs[64 * 64];   // 16 KB, chunk-swizzled: pos = c ^ (row&7)
    int t = threadIdx.x;
    int lane = t & 63, w = t >> 6;
    int m_off = (w >> 1) * 32, n_off = (w & 1) * 64;
    long long row0 = (long long)blockIdx.x * 64;
    f32x4 acc[2][4] = {};
    for (int k0i = 0; k0i < 4; ++k0i) {
        __syncthreads();
        #pragma unroll
        for (int i = 0; i < 4; ++i) {   // wave stages rows w*16 .. w*16+16
            int lrow = w * 16 + i * 4 + (lane >> 4);
            long long gr = row0 + lrow; if (gr >= N) gr = N - 1;
            int gchunk = (lane & 15) ^ (lrow & 7);
            gload_lds16(X + gr * IN_C + k0i * 64 + gchunk * 4,
                        xs + (w * 16 + i * 4) * 64);
        }
        __syncthreads();
        #pragma unroll
        for (int kk = 0; kk < 2; ++kk) {
            int kidx = k0i * 2 + kk;
            short8 ah[2], al[2], bh[4], bl[4];
            #pragma unroll
            for (int ni = 0; ni < 4; ++ni) {
                int nt = (n_off >> 4) + ni;
                const ushort* bp = wf1 + (size_t)(kidx * 16 + nt * 2) * 512 + lane * 8;
                bh[ni] = *(const short8*)bp;
                bl[ni] = *(const short8*)(bp + 512);
            }
            #pragma unroll
            for (int mi = 0; mi < 2; ++mi) {
                int r = m_off + mi * 16 + (lane & 15);
                int s = r & 7;
                int c0 = kk * 8 + (lane >> 4) * 2;
                float4 f0 = *(float4*)((char*)xs + r * 256 + ((c0 ^ s) * 16));
                float4 f1 = *(float4*)((char*)xs + r * 256 + (((c0 + 1) ^ s) * 16));
                cvt8(f0, f1, ah[mi], al[mi]);
            }
            #pragma unroll
            for (int mi = 0; mi < 2; ++mi)
                #pragma unroll
                for (int ni = 0; ni < 4; ++ni) {
                    acc[mi][ni] = __builtin_amdgcn_mfma_f32_16x16x32_bf16(ah[mi], bh[ni], acc[mi][ni], 0, 0, 0);
                    acc[mi][ni] = __builtin_amdgcn_mfma_f32_16x16x32_bf16(ah[mi], bl[ni], acc[mi][ni], 0, 0, 0);
                    acc[mi][ni] = __builtin_amdgcn_mfma_f32_16x16x32_bf16(al[mi], bh[ni], acc[mi][ni], 0, 0, 0);
                }
        }
    }
    int cr = (lane >> 4) * 4, cc = lane & 15;
    #pragma unroll
    for (int mi = 0; mi < 2; ++mi)
        #pragma unroll
        for (int j = 0; j < 4; ++j) {
            long long gr = row0 + m_off + mi * 16 + cr + j;
            if (gr < N) {
                float dv = dis[gr];
                #pragma unroll
                for (int ni = 0; ni < 4; ++ni) {
                    int col = n_off + ni * 16 + cc;
                    HB[gr * HID + col] = f2bf(acc[mi][ni][j] * dv);
                }
            }
        }
}

// ---- GEMM2: Hs2[N+1][64] = A2@W2 * dis (A2 = pre-split swizzled planes) ----
__global__ __launch_bounds__(256) void gemm2_mfma(const ushort* __restrict__ Ah,
                                                  const ushort* __restrict__ Al,
                                                  const ushort* __restrict__ wf2,
                                                  const float* __restrict__ dis,
                                                  ushort* __restrict__ HB, int N) {
    __shared__ ushort ash[64 * 64], asl[64 * 64];   // 8 KB each, swizzled
    int t = threadIdx.x;
    int lane = t & 63, w = t >> 6;
    int m_off = (w >> 1) * 32, n_off = (w & 1) * 32;
    long long row0 = (long long)blockIdx.x * 64;
    f32x4 acc[2][2] = {};
    for (int k0i = 0; k0i < 2; ++k0i) {
        __syncthreads();
        #pragma unroll
        for (int i = 0; i < 2; ++i) {   // wave stages rows w*16 .. w*16+16
            int rbase = w * 16 + i * 8;
            long long gr = row0 + rbase + (lane >> 3);
            size_t so = (size_t)gr * 128 + k0i * 64 + (lane & 7) * 8;
            gload_lds16(Ah + so, ash + rbase * 64);
            gload_lds16(Al + so, asl + rbase * 64);
        }
        __syncthreads();
        #pragma unroll
        for (int kk = 0; kk < 2; ++kk) {
            int kidx = k0i * 2 + kk;
            short8 ah[2], al[2], bh[2], bl[2];
            #pragma unroll
            for (int ni = 0; ni < 2; ++ni) {
                int nt = (n_off >> 4) + ni;
                const ushort* bp = wf2 + (size_t)(kidx * 8 + nt * 2) * 512 + lane * 8;
                bh[ni] = *(const short8*)bp;
                bl[ni] = *(const short8*)(bp + 512);
            }
            #pragma unroll
            for (int mi = 0; mi < 2; ++mi) {
                int r = m_off + mi * 16 + (lane & 15);
                int pos = (kk * 4 + (lane >> 4)) ^ (r & 7);
                ah[mi] = *(short8*)((char*)ash + r * 128 + pos * 16);
                al[mi] = *(short8*)((char*)asl + r * 128 + pos * 16);
            }
            #pragma unroll
            for (int mi = 0; mi < 2; ++mi)
                #pragma unroll
                for (int ni = 0; ni < 2; ++ni) {
                    acc[mi][ni] = __builtin_amdgcn_mfma_f32_16x16x32_bf16(ah[mi], bh[ni], acc[mi][ni], 0, 0, 0);
                    acc[mi][ni] = __builtin_amdgcn_mfma_f32_16x16x32_bf16(ah[mi], bl[ni], acc[mi][ni], 0, 0, 0);
                    acc[mi][ni] = __builtin_amdgcn_mfma_f32_16x16x32_bf16(al[mi], bh[ni], acc[mi][ni], 0, 0, 0);
                }
        }
    }
    int cr = (lane >> 4) * 4, cc = lane & 15;
    #pragma unroll
    for (int mi = 0; mi < 2; ++mi)
        #pragma unroll
        for (int j = 0; j < 4; ++j) {
            long long gr = row0 + m_off + mi * 16 + cr + j;
            if (gr < N) {
                float dv = dis[gr];
                #pragma unroll
                for (int ni = 0; ni < 2; ++ni)
                    HB[gr * OUTC + n_off + ni * 16 + cc] = f2bf(acc[mi][ni][j] * dv);
            }
        }
}

// ---- seg_agg layer 1: one node/wave, dword gathers over 128 feats ----------
__global__ __launch_bounds__(256) void seg_agg_l1(const ushort* __restrict__ H,
                                                  const float* __restrict__ dis,
                                                  const int2* __restrict__ rp2,
                                                  const int* __restrict__ epk,
                                                  const float* __restrict__ bias,
                                                  ushort* __restrict__ outH,
                                                  ushort* __restrict__ outL,
                                                  int N) {
    int lane = threadIdx.x & 63;
    int node = (int)(((long long)blockIdx.x * blockDim.x + threadIdx.x) >> 6);
    if (node >= N) return;
    const unsigned* hl = (const unsigned*)H + lane;   // row stride 64 uints
    unsigned v0 = hl[(size_t)node * 64];
    float a0 = bf2f((ushort)v0), a1 = bf2f((ushort)(v0 >> 16));
    int2 r2 = rp2[node];
    int e = r2.x, end = r2.x + r2.y;
    for (; e < end; e += 64) {
        int rem = end - e;                       // multiple of 16
        int rec = epk[min(e + lane, end - 1)];   // one coalesced 4B/lane load
        int m = min(64, rem);
        for (int u0 = 0; u0 < m; u0 += 16) {
            unsigned hv[16];
            #pragma unroll
            for (int u = 0; u < 16; ++u) {
                int s = __builtin_amdgcn_readlane(rec, u0 + u);
                hv[u] = hl[(size_t)s * 64];
            }
            #pragma unroll
            for (int u = 0; u < 16; ++u) {
                a0 += bf2f((ushort)hv[u]);
                a1 += bf2f((ushort)(hv[u] >> 16));
            }
        }
    }
    float dn = dis[node];
    int c0 = lane * 2;
    float2 bb = *(const float2*)&bias[c0];
    float p0 = fmaxf(dn * a0 + bb.x, 0.f);
    float p1 = fmaxf(dn * a1 + bb.y, 0.f);
    unsigned u0b = __float_as_uint(p0), u1b = __float_as_uint(p1);
    unsigned h0 = u0b >> 16, h1 = u1b >> 16;
    float r0 = p0 - __uint_as_float(u0b & 0xFFFF0000u);
    float r1 = p1 - __uint_as_float(u1b & 0xFFFF0000u);
    unsigned l0 = __float_as_uint(r0) >> 16, l1 = __float_as_uint(r1) >> 16;
    int sl = c0 >> 6, el = c0 & 63;
    int ch = ((el >> 3) ^ (node & 7));
    size_t pos = (size_t)node * 128 + sl * 64 + ch * 8 + (el & 7);
    *(unsigned*)&outH[pos] = h0 | (h1 << 16);
    *(unsigned*)&outL[pos] = l0 | (l1 << 16);
}

// ---- seg_agg layer 2: TWO nodes/wave (half-wave each, dword = 2 feats) -----
__global__ __launch_bounds__(256) void seg_agg_l2(const ushort* __restrict__ H,
                                                  const float* __restrict__ dis,
                                                  const int2* __restrict__ rp2,
                                                  const int* __restrict__ epk,
                                                  const float* __restrict__ bias,
                                                  float* __restrict__ outF,
                                                  int N) {
    int lane = threadIdx.x & 63;
    int wv = (int)(((long long)blockIdx.x * blockDim.x + threadIdx.x) >> 6);
    int n0 = wv * 2;
    if (n0 >= N) return;
    int n1 = n0 + 1;
    int has1 = (n1 < N);
    int half = lane >> 5;
    int myn = half ? (has1 ? n1 : N) : n0;       // sentinel N if no n1
    int f2 = (lane & 31) * 2;
    unsigned v0 = *(const unsigned*)&H[(size_t)myn * 64 + f2];
    float a0 = bf2f((ushort)v0), a1 = bf2f((ushort)(v0 >> 16));
    int2 rA = rp2[n0];
    int2 rB = has1 ? rp2[n1] : make_int2(0, 0);
    int eA = rA.x, endA = rA.x + rA.y;
    int eB = rB.x, endB = rB.x + rB.y;
    while (eA < endA || eB < endB) {
        int remA = endA - eA, remB = endB - eB;
        int mA = remA > 0 ? min(64, remA) : 0;
        int mB = remB > 0 ? min(64, remB) : 0;
        int recA = mA ? epk[min(eA + lane, endA - 1)] : 0;
        int recB = mB ? epk[min(eB + lane, endB - 1)] : 0;
        int m = max(mA, mB);                     // multiple of 16
        for (int u0 = 0; u0 < m; u0 += 16) {
            unsigned hv[16];
            #pragma unroll
            for (int u = 0; u < 16; ++u) {
                int idx = u0 + u;
                int sA = (idx < mA) ? __builtin_amdgcn_readlane(recA, idx) : N;
                int sB = (idx < mB) ? __builtin_amdgcn_readlane(recB, idx) : N;
                int s = half ? sB : sA;
                hv[u] = *(const unsigned*)&H[(size_t)s * 64 + f2];
            }
            #pragma unroll
            for (int u = 0; u < 16; ++u) {
                a0 += bf2f((ushort)hv[u]);
                a1 += bf2f((ushort)(hv[u] >> 16));
            }
        }
        eA += mA; eB += mB;
    }
    if (!half || has1) {
        int sn = half ? n1 : n0;
        float dn = dis[sn];
        float2 bb = *(const float2*)&bias[f2];
        float2 o;
        o.x = dn * a0 + bb.x;
        o.y = dn * a1 + bb.y;
        *(float2*)&outF[(size_t)sn * 64 + f2] = o;
    }
}

extern "C" void kernel_launch(void* const* d_in, const int* in_sizes, int n_in,
                              void* d_out, int out_size, void* d_ws, size_t ws_size,
                              hipStream_t stream) {
    const void*  ei = d_in[1];
    const float* x  = (const float*)d_in[0];
    const float* W1 = (const float*)d_in[2];
    const float* b1 = (const float*)d_in[3];
    const float* W2 = (const float*)d_in[4];
    const float* b2 = (const float*)d_in[5];
    float* out = (float*)d_out;
    int N = in_sizes[0] / IN_C;    // 50000
    int E = in_sizes[1] / 2;       // 800000
    int nb = (N + 255) >> 8;       // 196 dst buckets
    int nblk64 = (N + 63) / 64;    // 782
    int N_pad = nblk64 * 64;       // 50048

    char* ws = (char*)d_ws;
    size_t off = 0;
    auto alloc = [&](size_t bytes) {
        void* p = ws + off;
        off += ((bytes + 255) / 256) * 256;
        return p;
    };
    int*      blkcnt  = (int*)alloc((size_t)nb * NBLK * 4);
    int*      bbase   = (int*)alloc(((size_t)nb + 1) * 4);
    int2*     rp2     = (int2*)alloc((size_t)N * 8);
    float*    dis     = (float*)alloc((size_t)N * 4);
    unsigned* coarse  = (unsigned*)alloc((size_t)E * 4);
    int*      epk     = (int*)alloc(((size_t)E + (size_t)nb * 4096) * 4);
    ushort*   wf1     = (ushort*)alloc(131072);            // 128 KB frag-order
    ushort*   wf2     = (ushort*)alloc(32768);             // 32 KB frag-order
    ushort*   H1b     = (ushort*)alloc(((size_t)N + 1) * HID * 2);  // row-major
    ushort*   Ah      = (ushort*)alloc((size_t)N_pad * 128 * 2);
    ushort*   Al      = (ushort*)alloc((size_t)N_pad * 128 * 2);
    ushort*   H2b     = (ushort*)alloc(((size_t)N + 1) * OUTC * 2);

    ushort* h1sent = H1b + (size_t)N * HID;
    ushort* h2sent = H2b + (size_t)N * OUTC;
    void* args[] = { (void*)&ei, (void*)&W1, (void*)&W2, (void*)&wf1, (void*)&wf2,
                     (void*)&h1sent, (void*)&h2sent, (void*)&blkcnt, (void*)&bbase,
                     (void*)&rp2, (void*)&dis, (void*)&coarse, (void*)&epk,
                     (void*)&E, (void*)&N, (void*)&nb };
    hipLaunchCooperativeKernel((const void*)csr_coop, dim3(NBLK), dim3(256),
                               args, 0, stream);

    gemm1_mfma<<<nblk64, 256, 0, stream>>>(x, wf1, dis, H1b, N);
    int agg1_blocks = (int)(((long long)N * 64 + 255) / 256);
    seg_agg_l1<<<agg1_blocks, 256, 0, stream>>>(H1b, dis, rp2, epk, b1, Ah, Al, N);
    gemm2_mfma<<<nblk64, 256, 0, stream>>>(Ah, Al, wf2, dis, H2b, N);
    int waves2 = (N + 1) / 2;
    int agg2_blocks = (int)(((long long)waves2 * 64 + 255) / 256);
    seg_agg_l2<<<agg2_blocks, 256, 0, stream>>>(H2b, dis, rp2, epk, b2, out, N);
}

// Round 18
// 138.750 us; speedup vs baseline: 1.6951x; 1.6951x over previous
//
#include <hip/hip_runtime.h>

// GCN 2-layer encoder: N=50000 nodes, E=800000 edges, 256 -> 128 -> 64.
// Round 18: revert to round-16 structure (best: 139.2us). Cooperative fusion
// refuted (grid.sync ~100us overhead); separate launches are the cheap
// barrier. Sentinel-padded segments; layer-2 agg 2 nodes/wave; MFMA GEMMs
// with async-LDS staging + fragment-ordered W.

#define IN_C 256
#define HID 128
#define OUTC 64
#define NBLK 256    // blocks for bin_count/bin_scatter

typedef __attribute__((ext_vector_type(8))) short short8;
typedef __attribute__((ext_vector_type(4))) float f32x4;

// ---- async global -> LDS, 16B per lane (dst = wave-uniform base) -----------
__device__ __forceinline__ void gload_lds16(const void* src, void* dst) {
    __builtin_amdgcn_global_load_lds(
        (const __attribute__((address_space(1))) unsigned int*)src,
        (__attribute__((address_space(3))) unsigned int*)dst, 16, 0, 0);
}

// ---- fp32 -> bf16 hi/lo split (RTN, exact residual) ------------------------
__device__ __forceinline__ void bf16split(float f, ushort& h, ushort& l) {
    unsigned u = __float_as_uint(f);
    h = (ushort)(u >> 16);
    float hf = __uint_as_float(u & 0xFFFF0000u);
    unsigned v = __float_as_uint(f - hf);
    l = (ushort)((v + 0x7FFF + ((v >> 16) & 1)) >> 16);
}

// 8x fp32 -> hi/lo bf16 short8, trunc-lo variant
__device__ __forceinline__ void cvt8(float4 f0, float4 f1, short8& hi8, short8& lo8) {
    float ff[8];
    *(float4*)&ff[0] = f0; *(float4*)&ff[4] = f1;
    unsigned* hp = (unsigned*)&hi8;
    unsigned* lp = (unsigned*)&lo8;
    #pragma unroll
    for (int i = 0; i < 4; ++i) {
        unsigned u0 = __float_as_uint(ff[2 * i]), u1 = __float_as_uint(ff[2 * i + 1]);
        unsigned hf0 = u0 & 0xFFFF0000u, hf1 = u1 & 0xFFFF0000u;
        hp[i] = (u0 >> 16) | hf1;
        float r0 = ff[2 * i]     - __uint_as_float(hf0);
        float r1 = ff[2 * i + 1] - __uint_as_float(hf1);
        lp[i] = (__float_as_uint(r0) >> 16) | (__float_as_uint(r1) & 0xFFFF0000u);
    }
}

__device__ __forceinline__ ushort f2bf(float f) {
    unsigned u = __float_as_uint(f);
    return (ushort)((u + 0x7FFF + ((u >> 16) & 1)) >> 16);
}
__device__ __forceinline__ float bf2f(ushort u) {
    return __uint_as_float((unsigned)u << 16);
}

// ---- edge index access (int64 vs int32, detected per block) ----------------
__device__ __forceinline__ int edge_at(const void* ei, long long idx, int is32) {
    return is32 ? ((const int*)ei)[idx] : (int)((const long long*)ei)[idx];
}

__device__ __forceinline__ int detect32(const void* ei) {
    const unsigned long long* p = (const unsigned long long*)ei;
    int is32 = 0;
    for (int i = 0; i < 64; ++i)
        if (p[i] >> 32) { is32 = 1; break; }
    return is32;
}

// ---- W -> MFMA-fragment-ordered hi/lo planes + sentinel zeroing ------------
__global__ __launch_bounds__(256) void wtrans_kernel(const float* __restrict__ W1,
                                                     const float* __restrict__ W2,
                                                     ushort* __restrict__ wf1,
                                                     ushort* __restrict__ wf2,
                                                     ushort* __restrict__ h1sent,
                                                     ushort* __restrict__ h2sent) {
    int id = blockIdx.x * 256 + threadIdx.x;   // 0..10495
    if (id < 8192) {
        int lane = id & 63, r = id >> 6;       // r = kidx*16 + nt*2 + pl
        int pl = r & 1, nt = (r >> 1) & 7, kidx = r >> 4;
        int n = nt * 16 + (lane & 15);
        int kb = kidx * 32 + (lane >> 4) * 8;
        ushort v[8];
        #pragma unroll
        for (int j = 0; j < 8; ++j) {
            ushort h, l; bf16split(W1[(kb + j) * HID + n], h, l);
            v[j] = pl ? l : h;
        }
        *(short8*)&wf1[(size_t)id * 8] = *(short8*)v;
    } else if (id < 10240) {
        int id2 = id - 8192;
        int lane = id2 & 63, r = id2 >> 6;     // r = kidx*8 + nt*2 + pl
        int pl = r & 1, nt = (r >> 1) & 3, kidx = r >> 3;
        int n = nt * 16 + (lane & 15);
        int kb = kidx * 32 + (lane >> 4) * 8;
        ushort v[8];
        #pragma unroll
        for (int j = 0; j < 8; ++j) {
            ushort h, l; bf16split(W2[(kb + j) * OUTC + n], h, l);
            v[j] = pl ? l : h;
        }
        *(short8*)&wf2[(size_t)id2 * 8] = *(short8*)v;
    } else if (id < 10368) {
        h1sent[id - 10240] = 0;
    } else if (id < 10432) {
        h2sent[id - 10368] = 0;
    }
}

// ---- pass 1: per-block histogram over dst buckets (dst>>8) -----------------
__global__ __launch_bounds__(256) void bin_count(const void* ei,
                                                 int* __restrict__ blkcnt, int E, int nb) {
    __shared__ int h[256];
    __shared__ int s_is32;
    int t = threadIdx.x;
    h[t] = 0;
    if (t == 0) s_is32 = detect32(ei);
    __syncthreads();
    int is32 = s_is32;
    int chunk = (E + gridDim.x - 1) / gridDim.x;
    long long s0 = (long long)blockIdx.x * chunk;
    long long s1 = s0 + chunk; if (s1 > E) s1 = E;
    for (long long e = s0 + t; e < s1; e += 256) {
        int d = edge_at(ei, (long long)E + e, is32);
        atomicAdd(&h[d >> 8], 1);
    }
    __syncthreads();
    if (t < nb) blkcnt[t * NBLK + blockIdx.x] = h[t];
}

// ---- pass 2: per-bucket prefix over blocks + bucket-base scan (1 block) ----
__global__ __launch_bounds__(256) void bin_scan(int* __restrict__ blkcnt,
                                                int* __restrict__ bbase, int nb) {
    __shared__ int sh[256];
    int t = threadIdx.x;
    int tot = 0;
    if (t < nb) {
        int4* p = (int4*)&blkcnt[t * NBLK];
        int run = 0;
        for (int i = 0; i < NBLK / 4; ++i) {
            int4 v = p[i]; int4 o;
            o.x = run; run += v.x; o.y = run; run += v.y;
            o.z = run; run += v.z; o.w = run; run += v.w;
            p[i] = o;
        }
        tot = run;
    }
    sh[t] = tot;
    __syncthreads();
    for (int d = 1; d < 256; d <<= 1) {
        int add = (t >= d) ? sh[t - d] : 0;
        __syncthreads();
        sh[t] += add;
        __syncthreads();
    }
    if (t < nb) {
        bbase[t] = sh[t] - tot;              // exclusive
        if (t == nb - 1) bbase[nb] = sh[t];  // = E
    }
}

// ---- pass 3: scatter records into per-(block,bucket) contiguous segments ---
// record = src[17b] | dstlow8 << 17
__global__ __launch_bounds__(256) void bin_scatter(const void* ei,
                                                   const int* __restrict__ blkcnt,
                                                   const int* __restrict__ bbase,
                                                   unsigned* __restrict__ coarse, int E, int nb) {
    __shared__ int cur[256];
    __shared__ int s_is32;
    int t = threadIdx.x;
    if (t < nb) cur[t] = bbase[t] + blkcnt[t * NBLK + blockIdx.x];
    if (t == 0) s_is32 = detect32(ei);
    __syncthreads();
    int is32 = s_is32;
    int chunk = (E + gridDim.x - 1) / gridDim.x;
    long long s0 = (long long)blockIdx.x * chunk;
    long long s1 = s0 + chunk; if (s1 > E) s1 = E;
    for (long long e = s0 + t; e < s1; e += 256) {
        int s = edge_at(ei, e, is32);
        int d = edge_at(ei, (long long)E + e, is32);
        int p = atomicAdd(&cur[d >> 8], 1);
        coarse[p] = (unsigned)s | ((unsigned)(d & 255) << 17);
    }
}

// ---- pass 4: per-bucket exact sort by dst; PADDED segments -----------------
// Each node's edge run is padded to a multiple of 16 with sentinel src=N
// (zero row), so seg_agg's inner 16-batch needs no bounds checks.
// rp2[n] = {padded start, padded count}. Bucket b writes at bbase[b]+b*4096.
__global__ __launch_bounds__(256) void fine_kernel(const unsigned* __restrict__ coarse,
                                                   const int* __restrict__ bbase,
                                                   int2* __restrict__ rp2,
                                                   float* __restrict__ dis,
                                                   int* __restrict__ epk, int N, int nb) {
    __shared__ int h[256], cur[256], sh[256];
    int b = blockIdx.x, t = threadIdx.x;
    int nb0 = b << 8;
    int e0b = bbase[b], e1b = bbase[b + 1];
    int obase0 = e0b + b * 4096;
    h[t] = 0;
    __syncthreads();
    for (int e = e0b + t; e < e1b; e += 256)
        atomicAdd(&h[(coarse[e] >> 17) & 0xFF], 1);
    __syncthreads();
    int cnt = h[t];
    int pad = (cnt + 15) & ~15;
    sh[t] = pad;
    __syncthreads();
    for (int d = 1; d < 256; d <<= 1) {
        int add = (t >= d) ? sh[t - d] : 0;
        __syncthreads();
        sh[t] += add;
        __syncthreads();
    }
    int base = obase0 + sh[t] - pad;
    int node = nb0 + t;
    if (node < N) {
        rp2[node] = make_int2(base, pad);
        dis[node] = rsqrtf((float)cnt + 1.0f);   // +1 = self loop
    }
    cur[t] = base;
    __syncthreads();
    for (int e = e0b + t; e < e1b; e += 256) {
        unsigned r = coarse[e];
        int p = atomicAdd(&cur[(r >> 17) & 0xFF], 1);
        epk[p] = (int)(r & 0x1FFFF);
    }
    __syncthreads();
    for (int p = cur[t]; p < base + pad; ++p) epk[p] = N;   // sentinel fill
}

// ---- GEMM1: Hs[N+1][128] = (X@W1)*dis (row-major bf16) ---------------------
__global__ __launch_bounds__(256) void gemm1_mfma(const float* __restrict__ X,
                                                  const ushort* __restrict__ wf1,
                                                  const float* __restrict__ dis,
                                                  ushort* __restrict__ HB, int N) {
    __shared__ float xs[64 * 64];   // 16 KB, chunk-swizzled: pos = c ^ (row&7)
    int t = threadIdx.x;
    int lane = t & 63, w = t >> 6;
    int m_off = (w >> 1) * 32, n_off = (w & 1) * 64;
    long long row0 = (long long)blockIdx.x * 64;
    f32x4 acc[2][4] = {};
    for (int k0i = 0; k0i < 4; ++k0i) {
        __syncthreads();
        #pragma unroll
        for (int i = 0; i < 4; ++i) {   // wave stages rows w*16 .. w*16+16
            int lrow = w * 16 + i * 4 + (lane >> 4);
            long long gr = row0 + lrow; if (gr >= N) gr = N - 1;
            int gchunk = (lane & 15) ^ (lrow & 7);
            gload_lds16(X + gr * IN_C + k0i * 64 + gchunk * 4,
                        xs + (w * 16 + i * 4) * 64);
        }
        __syncthreads();
        #pragma unroll
        for (int kk = 0; kk < 2; ++kk) {
            int kidx = k0i * 2 + kk;
            short8 ah[2], al[2], bh[4], bl[4];
            #pragma unroll
            for (int ni = 0; ni < 4; ++ni) {
                int nt = (n_off >> 4) + ni;
                const ushort* bp = wf1 + (size_t)(kidx * 16 + nt * 2) * 512 + lane * 8;
                bh[ni] = *(const short8*)bp;
                bl[ni] = *(const short8*)(bp + 512);
            }
            #pragma unroll
            for (int mi = 0; mi < 2; ++mi) {
                int r = m_off + mi * 16 + (lane & 15);
                int s = r & 7;
                int c0 = kk * 8 + (lane >> 4) * 2;
                float4 f0 = *(float4*)((char*)xs + r * 256 + ((c0 ^ s) * 16));
                float4 f1 = *(float4*)((char*)xs + r * 256 + (((c0 + 1) ^ s) * 16));
                cvt8(f0, f1, ah[mi], al[mi]);
            }
            #pragma unroll
            for (int mi = 0; mi < 2; ++mi)
                #pragma unroll
                for (int ni = 0; ni < 4; ++ni) {
                    acc[mi][ni] = __builtin_amdgcn_mfma_f32_16x16x32_bf16(ah[mi], bh[ni], acc[mi][ni], 0, 0, 0);
                    acc[mi][ni] = __builtin_amdgcn_mfma_f32_16x16x32_bf16(ah[mi], bl[ni], acc[mi][ni], 0, 0, 0);
                    acc[mi][ni] = __builtin_amdgcn_mfma_f32_16x16x32_bf16(al[mi], bh[ni], acc[mi][ni], 0, 0, 0);
                }
        }
    }
    int cr = (lane >> 4) * 4, cc = lane & 15;
    #pragma unroll
    for (int mi = 0; mi < 2; ++mi)
        #pragma unroll
        for (int j = 0; j < 4; ++j) {
            long long gr = row0 + m_off + mi * 16 + cr + j;
            if (gr < N) {
                float dv = dis[gr];
                #pragma unroll
                for (int ni = 0; ni < 4; ++ni) {
                    int col = n_off + ni * 16 + cc;
                    HB[gr * HID + col] = f2bf(acc[mi][ni][j] * dv);
                }
            }
        }
}

// ---- GEMM2: Hs2[N+1][64] = A2@W2 * dis (A2 = pre-split swizzled planes) ----
__global__ __launch_bounds__(256) void gemm2_mfma(const ushort* __restrict__ Ah,
                                                  const ushort* __restrict__ Al,
                                                  const ushort* __restrict__ wf2,
                                                  const float* __restrict__ dis,
                                                  ushort* __restrict__ HB, int N) {
    __shared__ ushort ash[64 * 64], asl[64 * 64];   // 8 KB each, swizzled
    int t = threadIdx.x;
    int lane = t & 63, w = t >> 6;
    int m_off = (w >> 1) * 32, n_off = (w & 1) * 32;
    long long row0 = (long long)blockIdx.x * 64;
    f32x4 acc[2][2] = {};
    for (int k0i = 0; k0i < 2; ++k0i) {
        __syncthreads();
        #pragma unroll
        for (int i = 0; i < 2; ++i) {   // wave stages rows w*16 .. w*16+16
            int rbase = w * 16 + i * 8;
            long long gr = row0 + rbase + (lane >> 3);
            size_t so = (size_t)gr * 128 + k0i * 64 + (lane & 7) * 8;
            gload_lds16(Ah + so, ash + rbase * 64);
            gload_lds16(Al + so, asl + rbase * 64);
        }
        __syncthreads();
        #pragma unroll
        for (int kk = 0; kk < 2; ++kk) {
            int kidx = k0i * 2 + kk;
            short8 ah[2], al[2], bh[2], bl[2];
            #pragma unroll
            for (int ni = 0; ni < 2; ++ni) {
                int nt = (n_off >> 4) + ni;
                const ushort* bp = wf2 + (size_t)(kidx * 8 + nt * 2) * 512 + lane * 8;
                bh[ni] = *(const short8*)bp;
                bl[ni] = *(const short8*)(bp + 512);
            }
            #pragma unroll
            for (int mi = 0; mi < 2; ++mi) {
                int r = m_off + mi * 16 + (lane & 15);
                int pos = (kk * 4 + (lane >> 4)) ^ (r & 7);
                ah[mi] = *(short8*)((char*)ash + r * 128 + pos * 16);
                al[mi] = *(short8*)((char*)asl + r * 128 + pos * 16);
            }
            #pragma unroll
            for (int mi = 0; mi < 2; ++mi)
                #pragma unroll
                for (int ni = 0; ni < 2; ++ni) {
                    acc[mi][ni] = __builtin_amdgcn_mfma_f32_16x16x32_bf16(ah[mi], bh[ni], acc[mi][ni], 0, 0, 0);
                    acc[mi][ni] = __builtin_amdgcn_mfma_f32_16x16x32_bf16(ah[mi], bl[ni], acc[mi][ni], 0, 0, 0);
                    acc[mi][ni] = __builtin_amdgcn_mfma_f32_16x16x32_bf16(al[mi], bh[ni], acc[mi][ni], 0, 0, 0);
                }
        }
    }
    int cr = (lane >> 4) * 4, cc = lane & 15;
    #pragma unroll
    for (int mi = 0; mi < 2; ++mi)
        #pragma unroll
        for (int j = 0; j < 4; ++j) {
            long long gr = row0 + m_off + mi * 16 + cr + j;
            if (gr < N) {
                float dv = dis[gr];
                #pragma unroll
                for (int ni = 0; ni < 2; ++ni)
                    HB[gr * OUTC + n_off + ni * 16 + cc] = f2bf(acc[mi][ni][j] * dv);
            }
        }
}

// ---- seg_agg layer 1: one node/wave, dword gathers over 128 feats ----------
// Padded segments: inner 16-batch has NO bounds checks (pad slots read row N).
__global__ __launch_bounds__(256) void seg_agg_l1(const ushort* __restrict__ H,
                                                  const float* __restrict__ dis,
                                                  const int2* __restrict__ rp2,
                                                  const int* __restrict__ epk,
                                                  const float* __restrict__ bias,
                                                  ushort* __restrict__ outH,
                                                  ushort* __restrict__ outL,
                                                  int N) {
    int lane = threadIdx.x & 63;
    int node = (int)(((long long)blockIdx.x * blockDim.x + threadIdx.x) >> 6);
    if (node >= N) return;
    const unsigned* hl = (const unsigned*)H + lane;   // row stride 64 uints
    unsigned v0 = hl[(size_t)node * 64];
    float a0 = bf2f((ushort)v0), a1 = bf2f((ushort)(v0 >> 16));
    int2 r2 = rp2[node];
    int e = r2.x, end = r2.x + r2.y;
    for (; e < end; e += 64) {
        int rem = end - e;                       // multiple of 16
        int rec = epk[min(e + lane, end - 1)];   // one coalesced 4B/lane load
        int m = min(64, rem);
        for (int u0 = 0; u0 < m; u0 += 16) {
            unsigned hv[16];
            #pragma unroll
            for (int u = 0; u < 16; ++u) {
                int s = __builtin_amdgcn_readlane(rec, u0 + u);
                hv[u] = hl[(size_t)s * 64];
            }
            #pragma unroll
            for (int u = 0; u < 16; ++u) {
                a0 += bf2f((ushort)hv[u]);
                a1 += bf2f((ushort)(hv[u] >> 16));
            }
        }
    }
    float dn = dis[node];
    int c0 = lane * 2;
    float2 bb = *(const float2*)&bias[c0];
    float p0 = fmaxf(dn * a0 + bb.x, 0.f);
    float p1 = fmaxf(dn * a1 + bb.y, 0.f);
    unsigned u0b = __float_as_uint(p0), u1b = __float_as_uint(p1);
    unsigned h0 = u0b >> 16, h1 = u1b >> 16;
    float r0 = p0 - __uint_as_float(u0b & 0xFFFF0000u);
    float r1 = p1 - __uint_as_float(u1b & 0xFFFF0000u);
    unsigned l0 = __float_as_uint(r0) >> 16, l1 = __float_as_uint(r1) >> 16;
    int sl = c0 >> 6, el = c0 & 63;
    int ch = ((el >> 3) ^ (node & 7));
    size_t pos = (size_t)node * 128 + sl * 64 + ch * 8 + (el & 7);
    *(unsigned*)&outH[pos] = h0 | (h1 << 16);
    *(unsigned*)&outL[pos] = l0 | (l1 << 16);
}

// ---- seg_agg layer 2: TWO nodes/wave (half-wave each, dword = 2 feats) -----
// One gather instruction covers one edge of EACH node (loads/edge halved).
__global__ __launch_bounds__(256) void seg_agg_l2(const ushort* __restrict__ H,
                                                  const float* __restrict__ dis,
                                                  const int2* __restrict__ rp2,
                                                  const int* __restrict__ epk,
                                                  const float* __restrict__ bias,
                                                  float* __restrict__ outF,
                                                  int N) {
    int lane = threadIdx.x & 63;
    int wv = (int)(((long long)blockIdx.x * blockDim.x + threadIdx.x) >> 6);
    int n0 = wv * 2;
    if (n0 >= N) return;
    int n1 = n0 + 1;
    int has1 = (n1 < N);
    int half = lane >> 5;
    int myn = half ? (has1 ? n1 : N) : n0;       // sentinel N if no n1
    int f2 = (lane & 31) * 2;
    unsigned v0 = *(const unsigned*)&H[(size_t)myn * 64 + f2];
    float a0 = bf2f((ushort)v0), a1 = bf2f((ushort)(v0 >> 16));
    int2 rA = rp2[n0];
    int2 rB = has1 ? rp2[n1] : make_int2(0, 0);
    int eA = rA.x, endA = rA.x + rA.y;
    int eB = rB.x, endB = rB.x + rB.y;
    while (eA < endA || eB < endB) {
        int remA = endA - eA, remB = endB - eB;
        int mA = remA > 0 ? min(64, remA) : 0;
        int mB = remB > 0 ? min(64, remB) : 0;
        int recA = mA ? epk[min(eA + lane, endA - 1)] : 0;
        int recB = mB ? epk[min(eB + lane, endB - 1)] : 0;
        int m = max(mA, mB);                     // multiple of 16
        for (int u0 = 0; u0 < m; u0 += 16) {
            unsigned hv[16];
            #pragma unroll
            for (int u = 0; u < 16; ++u) {
                int idx = u0 + u;
                int sA = (idx < mA) ? __builtin_amdgcn_readlane(recA, idx) : N;
                int sB = (idx < mB) ? __builtin_amdgcn_readlane(recB, idx) : N;
                int s = half ? sB : sA;
                hv[u] = *(const unsigned*)&H[(size_t)s * 64 + f2];
            }
            #pragma unroll
            for (int u = 0; u < 16; ++u) {
                a0 += bf2f((ushort)hv[u]);
                a1 += bf2f((ushort)(hv[u] >> 16));
            }
        }
        eA += mA; eB += mB;
    }
    if (!half || has1) {
        int sn = half ? n1 : n0;
        float dn = dis[sn];
        float2 bb = *(const float2*)&bias[f2];
        float2 o;
        o.x = dn * a0 + bb.x;
        o.y = dn * a1 + bb.y;
        *(float2*)&outF[(size_t)sn * 64 + f2] = o;
    }
}

extern "C" void kernel_launch(void* const* d_in, const int* in_sizes, int n_in,
                              void* d_out, int out_size, void* d_ws, size_t ws_size,
                              hipStream_t stream) {
    const float* x  = (const float*)d_in[0];
    const void*  ei = d_in[1];
    const float* W1 = (const float*)d_in[2];
    const float* b1 = (const float*)d_in[3];
    const float* W2 = (const float*)d_in[4];
    const float* b2 = (const float*)d_in[5];
    float* out = (float*)d_out;
    int N = in_sizes[0] / IN_C;    // 50000
    int E = in_sizes[1] / 2;       // 800000
    int nb = (N + 255) >> 8;       // 196 dst buckets
    int nblk64 = (N + 63) / 64;    // 782
    int N_pad = nblk64 * 64;       // 50048

    char* ws = (char*)d_ws;
    size_t off = 0;
    auto alloc = [&](size_t bytes) {
        void* p = ws + off;
        off += ((bytes + 255) / 256) * 256;
        return p;
    };
    int*      blkcnt  = (int*)alloc((size_t)nb * NBLK * 4);
    int*      bbase   = (int*)alloc(((size_t)nb + 1) * 4);
    int2*     rp2     = (int2*)alloc((size_t)N * 8);
    float*    dis     = (float*)alloc((size_t)N * 4);
    unsigned* coarse  = (unsigned*)alloc((size_t)E * 4);
    int*      epk     = (int*)alloc(((size_t)E + (size_t)nb * 4096) * 4);
    ushort*   wf1     = (ushort*)alloc(131072);            // 128 KB frag-order
    ushort*   wf2     = (ushort*)alloc(32768);             // 32 KB frag-order
    ushort*   H1b     = (ushort*)alloc(((size_t)N + 1) * HID * 2);  // row-major
    ushort*   Ah      = (ushort*)alloc((size_t)N_pad * 128 * 2);
    ushort*   Al      = (ushort*)alloc((size_t)N_pad * 128 * 2);
    ushort*   H2b     = (ushort*)alloc(((size_t)N + 1) * OUTC * 2);

    wtrans_kernel<<<41, 256, 0, stream>>>(W1, W2, wf1, wf2,
                                          H1b + (size_t)N * HID,
                                          H2b + (size_t)N * OUTC);
    bin_count<<<NBLK, 256, 0, stream>>>(ei, blkcnt, E, nb);
    bin_scan<<<1, 256, 0, stream>>>(blkcnt, bbase, nb);
    bin_scatter<<<NBLK, 256, 0, stream>>>(ei, blkcnt, bbase, coarse, E, nb);
    fine_kernel<<<nb, 256, 0, stream>>>(coarse, bbase, rp2, dis, epk, N, nb);
    gemm1_mfma<<<nblk64, 256, 0, stream>>>(x, wf1, dis, H1b, N);

    int agg1_blocks = (int)(((long long)N * 64 + 255) / 256);
    seg_agg_l1<<<agg1_blocks, 256, 0, stream>>>(H1b, dis, rp2, epk, b1, Ah, Al, N);
    gemm2_mfma<<<nblk64, 256, 0, stream>>>(Ah, Al, wf2, dis, H2b, N);
    int waves2 = (N + 1) / 2;
    int agg2_blocks = (int)(((long long)waves2 * 64 + 255) / 256);
    seg_agg_l2<<<agg2_blocks, 256, 0, stream>>>(H2b, dis, rp2, epk, b2, out, N);
}